// Round 13
// baseline (146.621 us; speedup 1.0000x reference)
//
#include <hip/hip_runtime.h>
#include <math.h>

#define BGR  256      // graphs
#define NN   400      // nodes per graph (stage 1)
#define EPG  6400     // edges per graph

// ---------------------------------------------------------------------------
// GEMM: H = X @ W per graph-tile, XCD-aligned: grid (256 graphs, 7 tiles);
// linear block id = g + 256*t -> XCD = g%8.
// ---------------------------------------------------------------------------
template<int K>
__global__ __launch_bounds__(256) void gemm64x(const float* __restrict__ X,
                                               const float* __restrict__ W,
                                               float* __restrict__ H) {
  __shared__ float xs[64][K + 4];
  const int g = blockIdx.x, t = blockIdx.y;
  const int nrows = (t == 6) ? 16 : 64;
  const size_t rbase = (size_t)g * NN + t * 64;
  for (int i = threadIdx.x; i < 64 * (K / 4); i += 256) {
    int m = i / (K / 4), q = i % (K / 4);
    if (m < nrows)
      *reinterpret_cast<float4*>(&xs[m][q * 4]) =
          *reinterpret_cast<const float4*>(X + (rbase + m) * K + q * 4);
  }
  __syncthreads();
  const int c = threadIdx.x & 63;
  const int mg = (threadIdx.x >> 6) * 16;
  if (mg < nrows) {
    float acc[16];
#pragma unroll
    for (int i = 0; i < 16; ++i) acc[i] = 0.f;
    for (int k = 0; k < K; k += 4) {
      float w0 = W[(k + 0) * 64 + c];
      float w1 = W[(k + 1) * 64 + c];
      float w2 = W[(k + 2) * 64 + c];
      float w3 = W[(k + 3) * 64 + c];
#pragma unroll
      for (int i = 0; i < 16; ++i) {
        float4 xv = *reinterpret_cast<const float4*>(&xs[mg + i][k]);
        float a = acc[i];
        a = fmaf(xv.x, w0, a);
        a = fmaf(xv.y, w1, a);
        a = fmaf(xv.z, w2, a);
        a = fmaf(xv.w, w3, a);
        acc[i] = a;
      }
    }
#pragma unroll
    for (int i = 0; i < 16; ++i)
      H[(rbase + mg + i) * 64 + c] = acc[i];
  }
}

// ---------------------------------------------------------------------------
// Stage-1 conv, channel-split: grid (256 g, 2 halves), channels [h*32,+32).
// No long-lived per-thread edge/feature registers (spill-free): degree pass
// reads dst; CSR fill re-reads src/dst (L2-warm); h staged unscaled then
// scaled in place. LDS ~74.6 KB -> 2 blocks/CU.
// ---------------------------------------------------------------------------
__global__ __launch_bounds__(1024, 4) void conv1half(
    float* __restrict__ h1,
    const int* __restrict__ src, const int* __restrict__ dst,
    const float* __restrict__ b1, const float* __restrict__ pw1,
    float* __restrict__ scoreH) {
  __shared__ float          hl[401 * 32];      // 51,328 B (row 400 = 0)
  __shared__ __align__(16) unsigned short csr[9216];   // 18,432 B
  __shared__ int            off[NN + 1];
  __shared__ int            cur[NN];
  __shared__ float          dinv[NN];
  __shared__ int            wpart[8];

  const int g = blockIdx.x, half = blockIdx.y;
  const int tid = threadIdx.x;
  const int lane = tid & 63, wave = tid >> 6;
  const int e0 = g * EPG;
  const size_t hbase = (size_t)g * NN * 64 + half * 32;

  for (int i = tid; i < NN; i += 1024) cur[i] = 0;
  if (tid < 32) hl[400 * 32 + tid] = 0.f;
  __syncthreads();

  // stage h half (unscaled) + degree atomics
  for (int i = tid; i < NN * 8; i += 1024) {
    int n = i >> 3, q = (i & 7) * 4;
    *reinterpret_cast<float4*>(&hl[n * 32 + q]) =
        *reinterpret_cast<const float4*>(&h1[hbase + (size_t)n * 64 + q]);
  }
  for (int e = tid; e < EPG; e += 1024)
    atomicAdd(&cur[dst[e0 + e] - g * NN], 1);
  __syncthreads();

  // scan of padded degrees (x8); dinv
  int vincl = 0, myp = 0;
  if (tid < NN) {
    int d = cur[tid];
    dinv[tid] = 1.0f / sqrtf((float)d + 1.0f);
    myp = (d + 7) & ~7;
    vincl = myp;
#pragma unroll
    for (int o = 1; o < 64; o <<= 1) {
      int t = __shfl_up(vincl, o);
      if ((tid & 63) >= o) vincl += t;
    }
    if ((tid & 63) == 63 || tid == NN - 1) wpart[tid >> 6] = vincl;
  }
  __syncthreads();
  if (tid < NN) {
    int base = 0, w = tid >> 6;
    for (int j = 0; j < w; ++j) base += wpart[j];
    int incl = base + vincl;
    off[tid + 1] = incl;
    cur[tid] = incl - myp;
    if (tid == 0) off[0] = 0;
  }
  __syncthreads();

  // scale hl in place + csr fill (re-read edges, L2-warm)
  for (int i = tid; i < NN * 8; i += 1024) {
    int n = i >> 3, q = (i & 7) * 4;
    float dn = dinv[n];
    float4 v = *reinterpret_cast<const float4*>(&hl[n * 32 + q]);
    v.x *= dn; v.y *= dn; v.z *= dn; v.w *= dn;
    *reinterpret_cast<float4*>(&hl[n * 32 + q]) = v;
  }
  for (int e = tid; e < EPG; e += 1024) {
    int ls = src[e0 + e] - g * NN;
    int ld = dst[e0 + e] - g * NN;
    int p = atomicAdd(&cur[ld], 1);
    csr[p] = (unsigned short)(ls << 5);   // premult by 32
  }
  __syncthreads();
  if (tid < NN) {
    int pend = off[tid + 1];
    for (int p = cur[tid]; p < pend; ++p) csr[p] = (unsigned short)(400 * 32);
  }
  __syncthreads();

  // gather: wave-per-node; 8 edges per uint4 (4 per 32-lane sub)
  const int sub = lane >> 5, c = lane & 31;
  const float bc  = b1[half * 32 + c];
  const float pwc = pw1[half * 32 + c];
#pragma unroll
  for (int it = 0; it < 25; ++it) {
    int n = it * 16 + wave;
    int e = off[n], end = off[n + 1];
    float a0 = 0.f, a1 = 0.f;
    for (; e < end; e += 8) {
      uint4 pk = *reinterpret_cast<const uint4*>(&csr[e]);
      unsigned pa = sub ? pk.z : pk.x;
      unsigned pb = sub ? pk.w : pk.y;
      a0 += hl[(pa & 0xFFFF) + c];
      a1 += hl[(pa >> 16) + c];
      a0 += hl[(pb & 0xFFFF) + c];
      a1 += hl[(pb >> 16) + c];
    }
    float a = a0 + a1;
    a += __shfl_xor(a, 32);        // combine the two edge streams
    a += hl[n * 32 + c];           // self term
    float o = fmaxf(fmaf(a, dinv[n], bc), 0.f);
    if (sub == 0) h1[hbase + (size_t)n * 64 + c] = o;
    float sd = o * pwc;
    sd += __shfl_xor(sd, 1);
    sd += __shfl_xor(sd, 2);
    sd += __shfl_xor(sd, 4);
    sd += __shfl_xor(sd, 8);
    sd += __shfl_xor(sd, 16);
    if (lane == 0) scoreH[(g * NN + n) * 2 + half] = sd;
  }
}

// ---------------------------------------------------------------------------
// topk1 + stage2 + stage3 + readout. One block (1024 thr) per graph.
// No per-thread edge arrays: edges re-read per pass, remapped via lmap
// (composed with lmap2 for stage 3). W2/W3 from global (L1).
// ---------------------------------------------------------------------------
__global__ __launch_bounds__(1024, 4) void stage23(
    const float* __restrict__ h1post,
    const int* __restrict__ src, const int* __restrict__ dst,
    const float* __restrict__ scoreH, const float* __restrict__ pw1,
    const float* __restrict__ W2, const float* __restrict__ b2,
    const float* __restrict__ pw2,
    const float* __restrict__ W3, const float* __restrict__ b3,
    const float* __restrict__ Wl, const float* __restrict__ bl,
    float* __restrict__ out) {
  __shared__ float hp[100 * 64];          // 25,600 B; aliased by hpost2 later
  __shared__ float hl2[101 * 64];         // 25,856 B; later hp3/hl3
  __shared__ __align__(16) unsigned short csr[6656];   // 13,312 B
  __shared__ int   off[101];
  __shared__ int   cur[100];
  __shared__ float dinv[100];
  __shared__ __align__(16) float sc[NN];
  __shared__ int   sel[100];
  __shared__ int   lmap[NN];
  __shared__ int   lmap2[100];
  __shared__ float r1s[64], r2s[64];
  __shared__ float red[16][64];
  __shared__ int   wpart[2];
  __shared__ float nrm1_s, nrm2_s;

  const int g = blockIdx.x, tid = threadIdx.x;
  const int lane = tid & 63, wave = tid >> 6;
  const int e0 = g * EPG;
  const size_t hbase = (size_t)g * NN * 64;

  if (wave == 14) {
    float p = pw1[lane], t = p * p;
#pragma unroll
    for (int o = 32; o; o >>= 1) t += __shfl_xor(t, o);
    if (lane == 0) nrm1_s = sqrtf(t);
  }
  if (wave == 15) {
    float p = pw2[lane], t = p * p;
#pragma unroll
    for (int o = 32; o; o >>= 1) t += __shfl_xor(t, o);
    if (lane == 0) nrm2_s = sqrtf(t);
  }
  if (tid >= 512 && tid < 612) cur[tid - 512] = 0;
  __syncthreads();

  // combine score partials + tanh
  if (tid < NN) {
    float2 sv = *reinterpret_cast<const float2*>(&scoreH[(g * NN + tid) * 2]);
    sc[tid] = tanhf((sv.x + sv.y) / nrm1_s);
  }
  __syncthreads();

  // rank1 (stable, 2 nodes/thread, float4 broadcast)
  if (tid < 200) {
    int i0 = tid * 2, i1 = i0 + 1;
    float s0 = sc[i0], s1 = sc[i1];
    int rk0 = 0, rk1 = 0;
    for (int j4 = 0; j4 < 100; ++j4) {
      float4 sv = *reinterpret_cast<const float4*>(&sc[j4 * 4]);
      int jb = j4 * 4;
      rk0 += (sv.x > s0) || (sv.x == s0 && jb     < i0);
      rk0 += (sv.y > s0) || (sv.y == s0 && jb + 1 < i0);
      rk0 += (sv.z > s0) || (sv.z == s0 && jb + 2 < i0);
      rk0 += (sv.w > s0) || (sv.w == s0 && jb + 3 < i0);
      rk1 += (sv.x > s1) || (sv.x == s1 && jb     < i1);
      rk1 += (sv.y > s1) || (sv.y == s1 && jb + 1 < i1);
      rk1 += (sv.z > s1) || (sv.z == s1 && jb + 2 < i1);
      rk1 += (sv.w > s1) || (sv.w == s1 && jb + 3 < i1);
    }
    lmap[i0] = (rk0 < 100) ? rk0 : -1;
    if (rk0 < 100) sel[rk0] = i0;
    lmap[i1] = (rk1 < 100) ? rk1 : -1;
    if (rk1 < 100) sel[rk1] = i1;
  }
  __syncthreads();

  // hp gather from HBM (selected rows, scaled) + deg2 edge pass
  for (int i = tid; i < 1600; i += 1024) {
    int r = i >> 4, c4 = (i & 15) * 4;
    int n = sel[r];
    float s = sc[n];
    float4 v = *reinterpret_cast<const float4*>(&h1post[hbase + (size_t)n * 64 + c4]);
    v.x *= s; v.y *= s; v.z *= s; v.w *= s;
    *reinterpret_cast<float4*>(&hp[r * 64 + c4]) = v;
  }
  for (int e = tid; e < EPG; e += 1024) {
    int a = lmap[src[e0 + e] - g * NN];
    int b = lmap[dst[e0 + e] - g * NN];
    if ((a | b) >= 0) atomicAdd(&cur[b], 1);
  }
  __syncthreads();

  // r1 sums (wave-parallel)
  {
    float s = 0.f;
    for (int r = wave; r < 100; r += 16) s += hp[r * 64 + lane];
    red[wave][lane] = s;
  }
  __syncthreads();
  if (tid < 64) {
    float s = 0.f;
#pragma unroll
    for (int w = 0; w < 16; ++w) s += red[w][tid];
    r1s[tid] = s;
  }

  // scan2 (shfl, pad x2)
  {
    int d2 = 0, p2 = 0, v2s = 0;
    if (tid < 100) {
      d2 = cur[tid];
      p2 = (d2 + 1) & ~1;
      v2s = p2;
    }
#pragma unroll
    for (int o = 1; o < 64; o <<= 1) {
      int t = __shfl_up(v2s, o);
      if ((tid & 63) >= o) v2s += t;
    }
    if (tid < 100 && ((tid & 63) == 63 || tid == 99)) wpart[tid >> 6] = v2s;
    __syncthreads();
    if (tid < 100) {
      int base = (tid >= 64) ? wpart[0] : 0;
      int incl = base + v2s;
      dinv[tid] = 1.0f / sqrtf((float)d2 + 1.0f);
      off[tid + 1] = incl;
      cur[tid] = incl - p2;
      if (tid == 0) off[0] = 0;
    }
  }
  __syncthreads();

  // csr2 fill (edge pass 2)
  for (int e = tid; e < EPG; e += 1024) {
    int a = lmap[src[e0 + e] - g * NN];
    int b = lmap[dst[e0 + e] - g * NN];
    if ((a | b) >= 0) {
      int p = atomicAdd(&cur[b], 1);
      csr[p] = (unsigned short)(a << 6);
    }
  }
  __syncthreads();
  if (tid < 100) {
    int pend = off[tid + 1];
    for (int p = cur[tid]; p < pend; ++p) csr[p] = (unsigned short)(100 * 64);
  }
  if (tid < 64) hl2[100 * 64 + tid] = 0.f;
  __syncthreads();

  // gemm2: hl2 = dinv2 * (hp @ W2); W2 from global (L1)
  {
    float acc[7];
#pragma unroll
    for (int p = 0; p < 7; ++p) acc[p] = 0.f;
    for (int kb = 0; kb < 64; kb += 4) {
      float w0  = W2[(kb + 0) * 64 + lane];
      float w1  = W2[(kb + 1) * 64 + lane];
      float w2v = W2[(kb + 2) * 64 + lane];
      float w3v = W2[(kb + 3) * 64 + lane];
#pragma unroll
      for (int p = 0; p < 7; ++p) {
        int n = wave + p * 16;
        if (n < 100) {
          float4 hv = *reinterpret_cast<const float4*>(&hp[n * 64 + kb]);
          acc[p] = fmaf(hv.x, w0, acc[p]);
          acc[p] = fmaf(hv.y, w1, acc[p]);
          acc[p] = fmaf(hv.z, w2v, acc[p]);
          acc[p] = fmaf(hv.w, w3v, acc[p]);
        }
      }
    }
#pragma unroll
    for (int p = 0; p < 7; ++p) {
      int n = wave + p * 16;
      if (n < 100) hl2[n * 64 + lane] = dinv[n] * acc[p];
    }
  }
  __syncthreads();

  // gather2 + post (into hp region) + score
  float* hpost2 = hp;                      // hp dead after gemm2
  {
    const float bc2 = b2[lane], pwc2 = pw2[lane];
#pragma unroll
    for (int it = 0; it < 7; ++it) {
      int n = wave + it * 16;
      if (n < 100) {
        float a0 = hl2[n * 64 + lane], a1 = 0.f;
        int e = off[n], end = off[n + 1];
        for (; e < end; e += 2) {
          unsigned pk = *reinterpret_cast<const unsigned*>(&csr[e]);
          a0 += hl2[(pk & 0xFFFF) + lane];
          a1 += hl2[(pk >> 16) + lane];
        }
        float o = fmaxf(fmaf(a0 + a1, dinv[n], bc2), 0.f);
        hpost2[n * 64 + lane] = o;
        float sd = o * pwc2;
        sd += __shfl_xor(sd, 1);  sd += __shfl_xor(sd, 2);
        sd += __shfl_xor(sd, 4);  sd += __shfl_xor(sd, 8);
        sd += __shfl_xor(sd, 16); sd += __shfl_xor(sd, 32);
        if (lane == 0) sc[n] = tanhf(sd / nrm2_s);
      }
    }
  }
  __syncthreads();

  // rank2 (2 nodes/thread, float4 broadcast) -> lmap2; zero deg3
  if (tid < 50) {
    int i0 = tid * 2, i1 = i0 + 1;
    float s0 = sc[i0], s1 = sc[i1];
    int rk0 = 0, rk1 = 0;
    for (int j4 = 0; j4 < 25; ++j4) {
      float4 sv = *reinterpret_cast<const float4*>(&sc[j4 * 4]);
      int jb = j4 * 4;
      rk0 += (sv.x > s0) || (sv.x == s0 && jb     < i0);
      rk0 += (sv.y > s0) || (sv.y == s0 && jb + 1 < i0);
      rk0 += (sv.z > s0) || (sv.z == s0 && jb + 2 < i0);
      rk0 += (sv.w > s0) || (sv.w == s0 && jb + 3 < i0);
      rk1 += (sv.x > s1) || (sv.x == s1 && jb     < i1);
      rk1 += (sv.y > s1) || (sv.y == s1 && jb + 1 < i1);
      rk1 += (sv.z > s1) || (sv.z == s1 && jb + 2 < i1);
      rk1 += (sv.w > s1) || (sv.w == s1 && jb + 3 < i1);
    }
    lmap2[i0] = (rk0 < 25) ? rk0 : -1;
    if (rk0 < 25) sel[rk0] = i0;
    lmap2[i1] = (rk1 < 25) ? rk1 : -1;
    if (rk1 < 25) sel[rk1] = i1;
  }
  if (tid >= 512 && tid < 537) cur[tid - 512] = 0;
  __syncthreads();

  // hp3 extract (into hl2 region) + compose lmap for stage 3
  float* hp3 = hl2;                        // 1600 floats
  float* hl3 = hl2 + 1664;                 // 26 rows (row 25 = 0)
  if (tid < 400) {
    int r = tid >> 4, c4 = (tid & 15) * 4;
    int n = sel[r];
    float s = sc[n];
    float4 v = *reinterpret_cast<const float4*>(&hpost2[n * 64 + c4]);
    v.x *= s; v.y *= s; v.z *= s; v.w *= s;
    *reinterpret_cast<float4*>(&hp3[r * 64 + c4]) = v;
  }
  if (tid < NN) {
    int m = lmap[tid];
    lmap[tid] = (m >= 0) ? lmap2[m] : -1;
  }
  __syncthreads();

  // r2 sums (wave-parallel) + deg3 edge pass
  {
    float s = 0.f;
    for (int r = wave; r < 25; r += 16) s += hp3[r * 64 + lane];
    red[wave][lane] = s;
  }
  for (int e = tid; e < EPG; e += 1024) {
    int a = lmap[src[e0 + e] - g * NN];
    int b = lmap[dst[e0 + e] - g * NN];
    if ((a | b) >= 0) atomicAdd(&cur[b], 1);
  }
  __syncthreads();
  if (tid < 64) {
    float s = 0.f;
#pragma unroll
    for (int w = 0; w < 16; ++w) s += red[w][tid];
    r2s[tid] = s;
  }

  // scan3 (single-wave shfl, pad x2)
  {
    int d3 = 0, p3 = 0, v3s = 0;
    if (tid < 25) {
      d3 = cur[tid];
      p3 = (d3 + 1) & ~1;
      v3s = p3;
    }
    if (tid < 64) {
#pragma unroll
      for (int o = 1; o < 32; o <<= 1) {
        int t = __shfl_up(v3s, o);
        if (lane >= o) v3s += t;
      }
    }
    __syncthreads();
    if (tid < 25) {
      dinv[tid] = 1.0f / sqrtf((float)d3 + 1.0f);
      off[tid + 1] = v3s;
      cur[tid] = v3s - p3;
      if (tid == 0) off[0] = 0;
    }
  }
  __syncthreads();

  // csr3 fill (edge pass 4)
  for (int e = tid; e < EPG; e += 1024) {
    int a = lmap[src[e0 + e] - g * NN];
    int b = lmap[dst[e0 + e] - g * NN];
    if ((a | b) >= 0) {
      int p = atomicAdd(&cur[b], 1);
      csr[p] = (unsigned short)(a << 6);
    }
  }
  __syncthreads();
  if (tid < 25) {
    int pend = off[tid + 1];
    for (int p = cur[tid]; p < pend; ++p) csr[p] = (unsigned short)(25 * 64);
  }
  if (tid < 64) hl3[25 * 64 + tid] = 0.f;
  __syncthreads();

  // gemm3 (2 nodes/wave); W3 from global
  {
    float a0c = 0.f, a1c = 0.f;
    const int n1 = wave + 16;
    for (int kb = 0; kb < 64; kb += 4) {
      float w0  = W3[(kb + 0) * 64 + lane];
      float w1  = W3[(kb + 1) * 64 + lane];
      float w2v = W3[(kb + 2) * 64 + lane];
      float w3v = W3[(kb + 3) * 64 + lane];
      {
        float4 hv = *reinterpret_cast<const float4*>(&hp3[wave * 64 + kb]);
        a0c = fmaf(hv.x, w0, a0c);
        a0c = fmaf(hv.y, w1, a0c);
        a0c = fmaf(hv.z, w2v, a0c);
        a0c = fmaf(hv.w, w3v, a0c);
      }
      if (n1 < 25) {
        float4 hv = *reinterpret_cast<const float4*>(&hp3[n1 * 64 + kb]);
        a1c = fmaf(hv.x, w0, a1c);
        a1c = fmaf(hv.y, w1, a1c);
        a1c = fmaf(hv.z, w2v, a1c);
        a1c = fmaf(hv.w, w3v, a1c);
      }
    }
    if (wave < 25) hl3[wave * 64 + lane] = dinv[wave] * a0c;
    if (n1 < 25)  hl3[n1 * 64 + lane]  = dinv[n1] * a1c;
  }
  __syncthreads();

  // gather3 + r3 partials
  {
    const float bc3 = b3[lane];
    float part = 0.f;
#pragma unroll
    for (int it = 0; it < 2; ++it) {
      int n = wave + it * 16;
      if (n < 25) {
        float a0 = hl3[n * 64 + lane], a1 = 0.f;
        int e = off[n], end = off[n + 1];
        for (; e < end; e += 2) {
          unsigned pk = *reinterpret_cast<const unsigned*>(&csr[e]);
          a0 += hl3[(pk & 0xFFFF) + lane];
          a1 += hl3[(pk >> 16) + lane];
        }
        part += fmaxf(fmaf(a0 + a1, dinv[n], bc3), 0.f);
      }
    }
    red[wave][lane] = part;
  }
  __syncthreads();

  // final linear
  if (tid < 64) {
    float r3c = 0.f;
#pragma unroll
    for (int w = 0; w < 16; ++w) r3c += red[w][tid];
    float f1 = r2s[tid], f2 = r1s[tid];
    float p0 = r3c * Wl[tid * 2 + 0] + f1 * Wl[(64 + tid) * 2 + 0] + f2 * Wl[(128 + tid) * 2 + 0];
    float p1 = r3c * Wl[tid * 2 + 1] + f1 * Wl[(64 + tid) * 2 + 1] + f2 * Wl[(128 + tid) * 2 + 1];
#pragma unroll
    for (int o = 32; o; o >>= 1) {
      p0 += __shfl_xor(p0, o);
      p1 += __shfl_xor(p1, o);
    }
    if (tid == 0) {
      out[g * 2 + 0] = p0 + bl[0];
      out[g * 2 + 1] = p1 + bl[1];
    }
  }
}

// ---------------------------------------------------------------------------
extern "C" void kernel_launch(void* const* d_in, const int* in_sizes, int n_in,
                              void* d_out, int out_size, void* d_ws, size_t ws_size,
                              hipStream_t stream) {
  const float* x   = (const float*)d_in[0];
  const int*   src = (const int*)d_in[1];
  const int*   dst = (const int*)d_in[2];
  const float* W1  = (const float*)d_in[4];
  const float* b1  = (const float*)d_in[5];
  const float* W2  = (const float*)d_in[6];
  const float* b2  = (const float*)d_in[7];
  const float* W3  = (const float*)d_in[8];
  const float* b3  = (const float*)d_in[9];
  const float* pw1 = (const float*)d_in[10];
  const float* pw2 = (const float*)d_in[11];
  const float* Wl  = (const float*)d_in[12];
  const float* bl  = (const float*)d_in[13];
  float* out = (float*)d_out;

  float* h1     = (float*)d_ws;                   // 102400*64 f
  float* scoreH = h1 + (size_t)102400 * 64;       // 256*400*2 f

  gemm64x<128><<<dim3(BGR, 7), 256, 0, stream>>>(x, W1, h1);
  conv1half<<<dim3(BGR, 2), 1024, 0, stream>>>(h1, src, dst, b1, pw1, scoreH);
  stage23<<<BGR, 1024, 0, stream>>>(h1, src, dst, scoreH, pw1,
                                    W2, b2, pw2, W3, b3, Wl, bl, out);
}

// Round 14
// 128.831 us; speedup vs baseline: 1.1381x; 1.1381x over previous
//
#include <hip/hip_runtime.h>
#include <math.h>

#define BGR  256      // graphs
#define NN   400      // nodes per graph (stage 1)
#define EPG  6400     // edges per graph

// ---------------------------------------------------------------------------
// GEMM: H = X @ W per graph-tile, XCD-aligned: grid (256 graphs, 7 tiles);
// linear block id = g + 256*t -> XCD = g%8, matching mega's block g.
// ---------------------------------------------------------------------------
template<int K>
__global__ __launch_bounds__(256) void gemm64x(const float* __restrict__ X,
                                               const float* __restrict__ W,
                                               float* __restrict__ H) {
  __shared__ float xs[64][K + 4];
  const int g = blockIdx.x, t = blockIdx.y;
  const int nrows = (t == 6) ? 16 : 64;
  const size_t rbase = (size_t)g * NN + t * 64;
  for (int i = threadIdx.x; i < 64 * (K / 4); i += 256) {
    int m = i / (K / 4), q = i % (K / 4);
    if (m < nrows)
      *reinterpret_cast<float4*>(&xs[m][q * 4]) =
          *reinterpret_cast<const float4*>(X + (rbase + m) * K + q * 4);
  }
  __syncthreads();
  const int c = threadIdx.x & 63;
  const int mg = (threadIdx.x >> 6) * 16;
  if (mg < nrows) {
    float acc[16];
#pragma unroll
    for (int i = 0; i < 16; ++i) acc[i] = 0.f;
    for (int k = 0; k < K; k += 4) {
      float w0 = W[(k + 0) * 64 + c];
      float w1 = W[(k + 1) * 64 + c];
      float w2 = W[(k + 2) * 64 + c];
      float w3 = W[(k + 3) * 64 + c];
#pragma unroll
      for (int i = 0; i < 16; ++i) {
        float4 xv = *reinterpret_cast<const float4*>(&xs[mg + i][k]);
        float a = acc[i];
        a = fmaf(xv.x, w0, a);
        a = fmaf(xv.y, w1, a);
        a = fmaf(xv.z, w2, a);
        a = fmaf(xv.w, w3, a);
        acc[i] = a;
      }
    }
#pragma unroll
    for (int i = 0; i < 16; ++i)
      H[(rbase + mg + i) * 64 + c] = acc[i];
  }
}

// ---------------------------------------------------------------------------
// Mega-kernel: stages 1+2+3 fused, one block (1024 thr) per graph.
// Round-10 structure (best wall clock) + software-pipelined CSR prefetch in
// all gathers: load next 8/4 edge indices BEFORE consuming current ones,
// halving the per-iteration LDS-latency chain.
// ---------------------------------------------------------------------------
__global__ __launch_bounds__(1024, 4) void mega(
    const float* __restrict__ h1,
    const int* __restrict__ src, const int* __restrict__ dst,
    const float* __restrict__ b1, const float* __restrict__ pw1,
    const float* __restrict__ W2, const float* __restrict__ b2,
    const float* __restrict__ pw2,
    const float* __restrict__ W3, const float* __restrict__ b3,
    const float* __restrict__ Wl, const float* __restrict__ bl,
    float* __restrict__ out) {
  __shared__ float hl[401 * 64];                       // 102,656 B (row 400 = 0)
  __shared__ __align__(16) unsigned short csr[9216];   // 18,432 B
  __shared__ int   off[NN + 1];
  __shared__ int   cur[NN];
  __shared__ float dinv[NN];
  __shared__ __align__(16) float sc[NN];
  __shared__ int   sel[100];
  __shared__ int   lmap[NN];
  __shared__ float hp[100 * 64];                       // 25,600 B
  __shared__ float r1s[64], r2s[64];
  __shared__ int   wpart[8];
  __shared__ float nrm1_s, nrm2_s;

  const int g = blockIdx.x, tid = threadIdx.x;
  const int lane = tid & 63, wave = tid >> 6;
  const int e0 = g * EPG;
  const size_t hbase = (size_t)g * NN * 64;

  // ---- init: zero deg (cur), zero row 400, pw norms ----
  for (int i = tid; i < NN; i += 1024) cur[i] = 0;
  if (tid < 64) hl[400 * 64 + tid] = 0.f;
  if (wave == 14) {
    float p = pw1[lane], t = p * p;
#pragma unroll
    for (int o = 32; o; o >>= 1) t += __shfl_xor(t, o);
    if (lane == 0) nrm1_s = sqrtf(t);
  }
  if (wave == 15) {
    float p = pw2[lane], t = p * p;
#pragma unroll
    for (int o = 32; o; o >>= 1) t += __shfl_xor(t, o);
    if (lane == 0) nrm2_s = sqrtf(t);
  }
  __syncthreads();

  // ---- edges to regs + h1 prefetch + degree ----
  int es[7], ed[7];
#pragma unroll
  for (int u = 0; u < 7; ++u) {
    int e = tid + u * 1024;
    if (e < EPG) { es[u] = src[e0 + e] - g * NN; ed[u] = dst[e0 + e] - g * NN; }
    else         { es[u] = 0; ed[u] = -1; }
  }
  float4 hreg[7];
#pragma unroll
  for (int u = 0; u < 7; ++u) {
    int i = tid + u * 1024;
    if (i < NN * 16)
      hreg[u] = *reinterpret_cast<const float4*>(&h1[hbase + (size_t)i * 4]);
  }
#pragma unroll
  for (int u = 0; u < 7; ++u)
    if (ed[u] >= 0) atomicAdd(&cur[ed[u]], 1);
  __syncthreads();

  // ---- scan of padded degrees (x8); dinv ----
  int vincl = 0, myp = 0;
  if (tid < NN) {
    int d = cur[tid];
    dinv[tid] = 1.0f / sqrtf((float)d + 1.0f);
    myp = (d + 7) & ~7;
    vincl = myp;
#pragma unroll
    for (int o = 1; o < 64; o <<= 1) {
      int t = __shfl_up(vincl, o);
      if ((tid & 63) >= o) vincl += t;
    }
    if ((tid & 63) == 63 || tid == NN - 1) wpart[tid >> 6] = vincl;
  }
  __syncthreads();
  if (tid < NN) {
    int base = 0, w = tid >> 6;
    for (int j = 0; j < w; ++j) base += wpart[j];
    int incl = base + vincl;
    off[tid + 1] = incl;
    cur[tid] = incl - myp;
    if (tid == 0) off[0] = 0;
  }
  __syncthreads();

  // ---- stage hl (dinv-scaled) + csr fill ----
#pragma unroll
  for (int u = 0; u < 7; ++u) {
    int i = tid + u * 1024;
    if (i < NN * 16) {
      int n = i >> 4;
      float dn = dinv[n];
      float4 vv = hreg[u];
      vv.x *= dn; vv.y *= dn; vv.z *= dn; vv.w *= dn;
      *reinterpret_cast<float4*>(&hl[i * 4]) = vv;
    }
  }
#pragma unroll
  for (int u = 0; u < 7; ++u)
    if (ed[u] >= 0) {
      int p = atomicAdd(&cur[ed[u]], 1);
      csr[p] = (unsigned short)(es[u] << 6);
    }
  __syncthreads();
  if (tid < NN) {
    int pend = off[tid + 1];
    for (int p = cur[tid]; p < pend; ++p) csr[p] = (unsigned short)(400 * 64);
  }
  __syncthreads();

  // ---- gather1: wave-per-node, b32 rows, prefetched CSR; score fused ----
  {
    const float bc1 = b1[lane], pwc1 = pw1[lane];
    float outv[25];
#pragma unroll
    for (int it = 0; it < 25; ++it) {
      int n = it * 16 + wave;
      int e = off[n], end = off[n + 1];
      float a0 = hl[(n << 6) + lane], a1 = 0.f, a2 = 0.f, a3 = 0.f;
      if (e < end) {
        uint4 pk = *reinterpret_cast<const uint4*>(&csr[e]);
        for (e += 8; e < end; e += 8) {
          uint4 nx = *reinterpret_cast<const uint4*>(&csr[e]);
          a0 += hl[(pk.x & 0xFFFF) + lane];
          a1 += hl[(pk.x >> 16) + lane];
          a2 += hl[(pk.y & 0xFFFF) + lane];
          a3 += hl[(pk.y >> 16) + lane];
          a0 += hl[(pk.z & 0xFFFF) + lane];
          a1 += hl[(pk.z >> 16) + lane];
          a2 += hl[(pk.w & 0xFFFF) + lane];
          a3 += hl[(pk.w >> 16) + lane];
          pk = nx;
        }
        a0 += hl[(pk.x & 0xFFFF) + lane];
        a1 += hl[(pk.x >> 16) + lane];
        a2 += hl[(pk.y & 0xFFFF) + lane];
        a3 += hl[(pk.y >> 16) + lane];
        a0 += hl[(pk.z & 0xFFFF) + lane];
        a1 += hl[(pk.z >> 16) + lane];
        a2 += hl[(pk.w & 0xFFFF) + lane];
        a3 += hl[(pk.w >> 16) + lane];
      }
      float o = fmaxf(fmaf((a0 + a1) + (a2 + a3), dinv[n], bc1), 0.f);
      outv[it] = o;
      float sd = o * pwc1;
      sd += __shfl_xor(sd, 1);
      sd += __shfl_xor(sd, 2);
      sd += __shfl_xor(sd, 4);
      sd += __shfl_xor(sd, 8);
      sd += __shfl_xor(sd, 16);
      sd += __shfl_xor(sd, 32);
      if (lane == 0) sc[n] = tanhf(sd / nrm1_s);
    }
    __syncthreads();   // all reads of hl done
#pragma unroll
    for (int it = 0; it < 25; ++it)
      hl[((it * 16 + wave) << 6) + lane] = outv[it];
  }
  __syncthreads();

  // ---- rank1 (stable, 2 nodes/thread, float4 broadcast) ----
  if (tid < 200) {
    int i0 = tid * 2, i1 = i0 + 1;
    float s0 = sc[i0], s1 = sc[i1];
    int rk0 = 0, rk1 = 0;
    for (int j4 = 0; j4 < 100; ++j4) {
      float4 sv = *reinterpret_cast<const float4*>(&sc[j4 * 4]);
      int jb = j4 * 4;
      rk0 += (sv.x > s0) || (sv.x == s0 && jb     < i0);
      rk0 += (sv.y > s0) || (sv.y == s0 && jb + 1 < i0);
      rk0 += (sv.z > s0) || (sv.z == s0 && jb + 2 < i0);
      rk0 += (sv.w > s0) || (sv.w == s0 && jb + 3 < i0);
      rk1 += (sv.x > s1) || (sv.x == s1 && jb     < i1);
      rk1 += (sv.y > s1) || (sv.y == s1 && jb + 1 < i1);
      rk1 += (sv.z > s1) || (sv.z == s1 && jb + 2 < i1);
      rk1 += (sv.w > s1) || (sv.w == s1 && jb + 3 < i1);
    }
    lmap[i0] = (rk0 < 100) ? rk0 : -1;
    if (rk0 < 100) sel[rk0] = i0;
    lmap[i1] = (rk1 < 100) ? rk1 : -1;
    if (rk1 < 100) sel[rk1] = i1;
  }
  __syncthreads();

  // ---- hp extract (scaled) + edge remap + zero deg2 ----
  {
    int r = tid >> 4, c4 = (tid & 15) * 4;
    int n = sel[r];
    float s = sc[n];
    float4 vv = *reinterpret_cast<const float4*>(&hl[(n << 6) + c4]);
    vv.x *= s; vv.y *= s; vv.z *= s; vv.w *= s;
    *reinterpret_cast<float4*>(&hp[r * 64 + c4]) = vv;
    if (tid < 576) {
      int r2 = r + 64;
      int n2 = sel[r2];
      float s2 = sc[n2];
      float4 v2 = *reinterpret_cast<const float4*>(&hl[(n2 << 6) + c4]);
      v2.x *= s2; v2.y *= s2; v2.z *= s2; v2.w *= s2;
      *reinterpret_cast<float4*>(&hp[r2 * 64 + c4]) = v2;
    }
  }
#pragma unroll
  for (int u = 0; u < 7; ++u)
    if (ed[u] >= 0) {
      int a = lmap[es[u]], b = lmap[ed[u]];
      if ((a | b) >= 0) { es[u] = a; ed[u] = b; } else ed[u] = -1;
    }
  if (tid >= 512 && tid < 612) cur[tid - 512] = 0;
  __syncthreads();

  // ---- r1 sums + deg2 ----
  if (tid < 64) {
    float s = 0.f;
    for (int r = 0; r < 100; ++r) s += hp[r * 64 + tid];
    r1s[tid] = s;
  }
#pragma unroll
  for (int u = 0; u < 7; ++u)
    if (ed[u] >= 0) atomicAdd(&cur[ed[u]], 1);
  __syncthreads();

  // ---- scan2 (shfl, pad x4) ----
  {
    int d2 = 0, p2 = 0, v2s = 0;
    if (tid < 100) {
      d2 = cur[tid];
      p2 = (d2 + 3) & ~3;
      v2s = p2;
    }
#pragma unroll
    for (int o = 1; o < 64; o <<= 1) {
      int t = __shfl_up(v2s, o);
      if ((tid & 63) >= o) v2s += t;
    }
    if (tid < 100 && ((tid & 63) == 63 || tid == 99)) wpart[tid >> 6] = v2s;
    __syncthreads();
    if (tid < 100) {
      int base = (tid >= 64) ? wpart[0] : 0;
      int incl = base + v2s;
      dinv[tid] = 1.0f / sqrtf((float)d2 + 1.0f);
      off[tid + 1] = incl;
      cur[tid] = incl - p2;
      if (tid == 0) off[0] = 0;
    }
  }
  __syncthreads();
#pragma unroll
  for (int u = 0; u < 7; ++u)
    if (ed[u] >= 0) {
      int p = atomicAdd(&cur[ed[u]], 1);
      csr[p] = (unsigned short)(es[u] << 6);
    }
  __syncthreads();
  float* Ws = hl;                           // 4096 floats
  float* hl2 = hl + 4096;                   // 101 rows (row 100 = 0)
  float* hpost2 = hl + 4096 + 101 * 64;     // 100 rows
  if (tid < 100) {
    int pend = off[tid + 1];
    for (int p = cur[tid]; p < pend; ++p) csr[p] = (unsigned short)(100 * 64);
  }
  for (int i = tid; i < 4096; i += 1024) Ws[i] = W2[i];
  if (tid < 64) hl2[100 * 64 + tid] = 0.f;
  __syncthreads();

  // ---- gemm2: hl2 = dinv2 * (hp @ W2) ----
  {
    float acc[7];
#pragma unroll
    for (int p = 0; p < 7; ++p) acc[p] = 0.f;
    for (int kb = 0; kb < 64; kb += 4) {
      float w0  = Ws[(kb + 0) * 64 + lane];
      float w1  = Ws[(kb + 1) * 64 + lane];
      float w2v = Ws[(kb + 2) * 64 + lane];
      float w3v = Ws[(kb + 3) * 64 + lane];
#pragma unroll
      for (int p = 0; p < 7; ++p) {
        int n = wave + p * 16;
        if (n < 100) {
          float4 hv = *reinterpret_cast<const float4*>(&hp[n * 64 + kb]);
          acc[p] = fmaf(hv.x, w0, acc[p]);
          acc[p] = fmaf(hv.y, w1, acc[p]);
          acc[p] = fmaf(hv.z, w2v, acc[p]);
          acc[p] = fmaf(hv.w, w3v, acc[p]);
        }
      }
    }
#pragma unroll
    for (int p = 0; p < 7; ++p) {
      int n = wave + p * 16;
      if (n < 100) hl2[n * 64 + lane] = dinv[n] * acc[p];
    }
  }
  __syncthreads();

  // ---- gather2 + post + score (prefetched CSR) ----
  {
    const float bc2 = b2[lane], pwc2 = pw2[lane];
#pragma unroll
    for (int it = 0; it < 7; ++it) {
      int n = wave + it * 16;
      if (n < 100) {
        float a0 = hl2[n * 64 + lane], a1 = 0.f;
        int e = off[n], end = off[n + 1];
        if (e < end) {
          unsigned pk = *reinterpret_cast<const unsigned*>(&csr[e]);
          unsigned pk2 = *reinterpret_cast<const unsigned*>(&csr[e + 2]);
          for (e += 4; e < end; e += 4) {
            unsigned nx  = *reinterpret_cast<const unsigned*>(&csr[e]);
            unsigned nx2 = *reinterpret_cast<const unsigned*>(&csr[e + 2]);
            a0 += hl2[(pk & 0xFFFF) + lane];
            a1 += hl2[(pk >> 16) + lane];
            a0 += hl2[(pk2 & 0xFFFF) + lane];
            a1 += hl2[(pk2 >> 16) + lane];
            pk = nx; pk2 = nx2;
          }
          a0 += hl2[(pk & 0xFFFF) + lane];
          a1 += hl2[(pk >> 16) + lane];
          a0 += hl2[(pk2 & 0xFFFF) + lane];
          a1 += hl2[(pk2 >> 16) + lane];
        }
        float o = fmaxf(fmaf(a0 + a1, dinv[n], bc2), 0.f);
        hpost2[n * 64 + lane] = o;
        float sd = o * pwc2;
        sd += __shfl_xor(sd, 1);  sd += __shfl_xor(sd, 2);
        sd += __shfl_xor(sd, 4);  sd += __shfl_xor(sd, 8);
        sd += __shfl_xor(sd, 16); sd += __shfl_xor(sd, 32);
        if (lane == 0) sc[n] = tanhf(sd / nrm2_s);
      }
    }
  }
  __syncthreads();

  // ---- rank2 (2 nodes/thread, float4 broadcast) ----
  if (tid < 50) {
    int i0 = tid * 2, i1 = i0 + 1;
    float s0 = sc[i0], s1 = sc[i1];
    int rk0 = 0, rk1 = 0;
    for (int j4 = 0; j4 < 25; ++j4) {
      float4 sv = *reinterpret_cast<const float4*>(&sc[j4 * 4]);
      int jb = j4 * 4;
      rk0 += (sv.x > s0) || (sv.x == s0 && jb     < i0);
      rk0 += (sv.y > s0) || (sv.y == s0 && jb + 1 < i0);
      rk0 += (sv.z > s0) || (sv.z == s0 && jb + 2 < i0);
      rk0 += (sv.w > s0) || (sv.w == s0 && jb + 3 < i0);
      rk1 += (sv.x > s1) || (sv.x == s1 && jb     < i1);
      rk1 += (sv.y > s1) || (sv.y == s1 && jb + 1 < i1);
      rk1 += (sv.z > s1) || (sv.z == s1 && jb + 2 < i1);
      rk1 += (sv.w > s1) || (sv.w == s1 && jb + 3 < i1);
    }
    lmap[i0] = (rk0 < 25) ? rk0 : -1;
    if (rk0 < 25) sel[rk0] = i0;
    lmap[i1] = (rk1 < 25) ? rk1 : -1;
    if (rk1 < 25) sel[rk1] = i1;
  }
  __syncthreads();

  // ---- hp2 extract + remap + zero deg3 ----
  if (tid < 400) {
    int r = tid >> 4, c4 = (tid & 15) * 4;
    int n = sel[r];
    float s = sc[n];
    float4 vv = *reinterpret_cast<const float4*>(&hpost2[n * 64 + c4]);
    vv.x *= s; vv.y *= s; vv.z *= s; vv.w *= s;
    *reinterpret_cast<float4*>(&hp[r * 64 + c4]) = vv;
  }
#pragma unroll
  for (int u = 0; u < 7; ++u)
    if (ed[u] >= 0) {
      int a = lmap[es[u]], b = lmap[ed[u]];
      if ((a | b) >= 0) { es[u] = a; ed[u] = b; } else ed[u] = -1;
    }
  if (tid >= 512 && tid < 537) cur[tid - 512] = 0;
  __syncthreads();

  // ---- r2 sums + deg3 ----
  if (tid < 64) {
    float s = 0.f;
    for (int r = 0; r < 25; ++r) s += hp[r * 64 + tid];
    r2s[tid] = s;
  }
#pragma unroll
  for (int u = 0; u < 7; ++u)
    if (ed[u] >= 0) atomicAdd(&cur[ed[u]], 1);
  __syncthreads();

  // ---- scan3 (single-wave shfl, pad x4) ----
  {
    int d3 = 0, p3 = 0, v3s = 0;
    if (tid < 25) {
      d3 = cur[tid];
      p3 = (d3 + 3) & ~3;
      v3s = p3;
    }
    if (tid < 64) {
#pragma unroll
      for (int o = 1; o < 32; o <<= 1) {
        int t = __shfl_up(v3s, o);
        if (lane >= o) v3s += t;
      }
    }
    __syncthreads();
    if (tid < 25) {
      dinv[tid] = 1.0f / sqrtf((float)d3 + 1.0f);
      off[tid + 1] = v3s;
      cur[tid] = v3s - p3;
      if (tid == 0) off[0] = 0;
    }
  }
  __syncthreads();
#pragma unroll
  for (int u = 0; u < 7; ++u)
    if (ed[u] >= 0) {
      int p = atomicAdd(&cur[ed[u]], 1);
      csr[p] = (unsigned short)(es[u] << 6);
    }
  __syncthreads();
  float* hl3 = hl + 4096;                   // 26 rows (row 25 = 0)
  if (tid < 25) {
    int pend = off[tid + 1];
    for (int p = cur[tid]; p < pend; ++p) csr[p] = (unsigned short)(25 * 64);
  }
  for (int i = tid; i < 4096; i += 1024) Ws[i] = W3[i];
  if (tid < 64) hl3[25 * 64 + tid] = 0.f;
  __syncthreads();

  // ---- gemm3 (P=2) ----
  {
    float a0c = 0.f, a1c = 0.f;
    const int n1 = wave + 16;
    for (int kb = 0; kb < 64; kb += 4) {
      float w0  = Ws[(kb + 0) * 64 + lane];
      float w1  = Ws[(kb + 1) * 64 + lane];
      float w2v = Ws[(kb + 2) * 64 + lane];
      float w3v = Ws[(kb + 3) * 64 + lane];
      {
        float4 hv = *reinterpret_cast<const float4*>(&hp[wave * 64 + kb]);
        a0c = fmaf(hv.x, w0, a0c);
        a0c = fmaf(hv.y, w1, a0c);
        a0c = fmaf(hv.z, w2v, a0c);
        a0c = fmaf(hv.w, w3v, a0c);
      }
      if (n1 < 25) {
        float4 hv = *reinterpret_cast<const float4*>(&hp[n1 * 64 + kb]);
        a1c = fmaf(hv.x, w0, a1c);
        a1c = fmaf(hv.y, w1, a1c);
        a1c = fmaf(hv.z, w2v, a1c);
        a1c = fmaf(hv.w, w3v, a1c);
      }
    }
    hl3[wave * 64 + lane] = dinv[wave] * a0c;
    if (n1 < 25) hl3[n1 * 64 + lane] = dinv[n1] * a1c;
  }
  __syncthreads();

  // ---- gather3 + r3 partials (prefetched CSR) ----
  {
    const float bc3 = b3[lane];
    float part = 0.f;
#pragma unroll
    for (int it = 0; it < 2; ++it) {
      int n = wave + it * 16;
      if (n < 25) {
        float a0 = hl3[n * 64 + lane], a1 = 0.f;
        int e = off[n], end = off[n + 1];
        if (e < end) {
          unsigned pk = *reinterpret_cast<const unsigned*>(&csr[e]);
          unsigned pk2 = *reinterpret_cast<const unsigned*>(&csr[e + 2]);
          for (e += 4; e < end; e += 4) {
            unsigned nx  = *reinterpret_cast<const unsigned*>(&csr[e]);
            unsigned nx2 = *reinterpret_cast<const unsigned*>(&csr[e + 2]);
            a0 += hl3[(pk & 0xFFFF) + lane];
            a1 += hl3[(pk >> 16) + lane];
            a0 += hl3[(pk2 & 0xFFFF) + lane];
            a1 += hl3[(pk2 >> 16) + lane];
            pk = nx; pk2 = nx2;
          }
          a0 += hl3[(pk & 0xFFFF) + lane];
          a1 += hl3[(pk >> 16) + lane];
          a0 += hl3[(pk2 & 0xFFFF) + lane];
          a1 += hl3[(pk2 >> 16) + lane];
        }
        part += fmaxf(fmaf(a0 + a1, dinv[n], bc3), 0.f);
      }
    }
    float* red = hl + 8192;
    red[wave * 64 + lane] = part;
  }
  __syncthreads();

  // ---- final linear ----
  if (tid < 64) {
    float* red = hl + 8192;
    float r3c = 0.f;
#pragma unroll
    for (int w = 0; w < 16; ++w) r3c += red[w * 64 + tid];
    float f1 = r2s[tid], f2 = r1s[tid];
    float p0 = r3c * Wl[tid * 2 + 0] + f1 * Wl[(64 + tid) * 2 + 0] + f2 * Wl[(128 + tid) * 2 + 0];
    float p1 = r3c * Wl[tid * 2 + 1] + f1 * Wl[(64 + tid) * 2 + 1] + f2 * Wl[(128 + tid) * 2 + 1];
#pragma unroll
    for (int o = 32; o; o >>= 1) {
      p0 += __shfl_xor(p0, o);
      p1 += __shfl_xor(p1, o);
    }
    if (tid == 0) {
      out[g * 2 + 0] = p0 + bl[0];
      out[g * 2 + 1] = p1 + bl[1];
    }
  }
}

// ---------------------------------------------------------------------------
extern "C" void kernel_launch(void* const* d_in, const int* in_sizes, int n_in,
                              void* d_out, int out_size, void* d_ws, size_t ws_size,
                              hipStream_t stream) {
  const float* x   = (const float*)d_in[0];
  const int*   src = (const int*)d_in[1];
  const int*   dst = (const int*)d_in[2];
  const float* W1  = (const float*)d_in[4];
  const float* b1  = (const float*)d_in[5];
  const float* W2  = (const float*)d_in[6];
  const float* b2  = (const float*)d_in[7];
  const float* W3  = (const float*)d_in[8];
  const float* b3  = (const float*)d_in[9];
  const float* pw1 = (const float*)d_in[10];
  const float* pw2 = (const float*)d_in[11];
  const float* Wl  = (const float*)d_in[12];
  const float* bl  = (const float*)d_in[13];
  float* out = (float*)d_out;

  float* h1 = (float*)d_ws;   // 102400 x 64 floats

  gemm64x<128><<<dim3(BGR, 7), 256, 0, stream>>>(x, W1, h1);
  mega<<<BGR, 1024, 0, stream>>>(h1, src, dst, b1, pw1, W2, b2, pw2,
                                 W3, b3, Wl, bl, out);
}

// Round 15
// 126.600 us; speedup vs baseline: 1.1581x; 1.0176x over previous
//
#include <hip/hip_runtime.h>
#include <math.h>

#define BGR  256      // graphs
#define NN   400      // nodes per graph (stage 1)
#define EPG  6400     // edges per graph

// ---------------------------------------------------------------------------
// GEMM: H = X @ W per graph-tile, XCD-aligned: grid (256 graphs, 7 tiles);
// linear block id = g + 256*t -> XCD = g%8, matching mega's block g.
// ---------------------------------------------------------------------------
template<int K>
__global__ __launch_bounds__(256) void gemm64x(const float* __restrict__ X,
                                               const float* __restrict__ W,
                                               float* __restrict__ H) {
  __shared__ float xs[64][K + 4];
  const int g = blockIdx.x, t = blockIdx.y;
  const int nrows = (t == 6) ? 16 : 64;
  const size_t rbase = (size_t)g * NN + t * 64;
  for (int i = threadIdx.x; i < 64 * (K / 4); i += 256) {
    int m = i / (K / 4), q = i % (K / 4);
    if (m < nrows)
      *reinterpret_cast<float4*>(&xs[m][q * 4]) =
          *reinterpret_cast<const float4*>(X + (rbase + m) * K + q * 4);
  }
  __syncthreads();
  const int c = threadIdx.x & 63;
  const int mg = (threadIdx.x >> 6) * 16;
  if (mg < nrows) {
    float acc[16];
#pragma unroll
    for (int i = 0; i < 16; ++i) acc[i] = 0.f;
    for (int k = 0; k < K; k += 4) {
      float w0 = W[(k + 0) * 64 + c];
      float w1 = W[(k + 1) * 64 + c];
      float w2 = W[(k + 2) * 64 + c];
      float w3 = W[(k + 3) * 64 + c];
#pragma unroll
      for (int i = 0; i < 16; ++i) {
        float4 xv = *reinterpret_cast<const float4*>(&xs[mg + i][k]);
        float a = acc[i];
        a = fmaf(xv.x, w0, a);
        a = fmaf(xv.y, w1, a);
        a = fmaf(xv.z, w2, a);
        a = fmaf(xv.w, w3, a);
        acc[i] = a;
      }
    }
#pragma unroll
    for (int i = 0; i < 16; ++i)
      H[(rbase + mg + i) * 64 + c] = acc[i];
  }
}

// ---------------------------------------------------------------------------
// Mega-kernel: stages 1+2+3 fused, one block (1024 thr) per graph.
// Round-10 structure + wide narrow-phases: rank1 800 thr (2/node), rank2
// 400 thr (4/node), r1/r2 sums 16-wave parallel (combined during scans),
// gemm2/3 weights read from global (L1) - no LDS staging phases.
// ---------------------------------------------------------------------------
__global__ __launch_bounds__(1024, 4) void mega(
    const float* __restrict__ h1,
    const int* __restrict__ src, const int* __restrict__ dst,
    const float* __restrict__ b1, const float* __restrict__ pw1,
    const float* __restrict__ W2, const float* __restrict__ b2,
    const float* __restrict__ pw2,
    const float* __restrict__ W3, const float* __restrict__ b3,
    const float* __restrict__ Wl, const float* __restrict__ bl,
    float* __restrict__ out) {
  __shared__ float hl[401 * 64];                       // 102,656 B (row 400 = 0)
  __shared__ __align__(16) unsigned short csr[9216];   // 18,432 B
  __shared__ int   off[NN + 1];
  __shared__ int   cur[NN];
  __shared__ float dinv[NN];
  __shared__ __align__(16) float sc[NN];
  __shared__ int   sel[100];
  __shared__ int   lmap[NN];
  __shared__ float hp[100 * 64];                       // 25,600 B
  __shared__ float r1s[64], r2s[64];
  __shared__ int   wpart[8];
  __shared__ float nrm1_s, nrm2_s;

  const int g = blockIdx.x, tid = threadIdx.x;
  const int lane = tid & 63, wave = tid >> 6;
  const int e0 = g * EPG;
  const size_t hbase = (size_t)g * NN * 64;

  // ---- init: zero deg (cur), zero row 400, pw norms ----
  for (int i = tid; i < NN; i += 1024) cur[i] = 0;
  if (tid < 64) hl[400 * 64 + tid] = 0.f;
  if (wave == 14) {
    float p = pw1[lane], t = p * p;
#pragma unroll
    for (int o = 32; o; o >>= 1) t += __shfl_xor(t, o);
    if (lane == 0) nrm1_s = sqrtf(t);
  }
  if (wave == 15) {
    float p = pw2[lane], t = p * p;
#pragma unroll
    for (int o = 32; o; o >>= 1) t += __shfl_xor(t, o);
    if (lane == 0) nrm2_s = sqrtf(t);
  }
  __syncthreads();

  // ---- edges to regs + h1 prefetch + degree ----
  int es[7], ed[7];
#pragma unroll
  for (int u = 0; u < 7; ++u) {
    int e = tid + u * 1024;
    if (e < EPG) { es[u] = src[e0 + e] - g * NN; ed[u] = dst[e0 + e] - g * NN; }
    else         { es[u] = 0; ed[u] = -1; }
  }
  float4 hreg[7];
#pragma unroll
  for (int u = 0; u < 7; ++u) {
    int i = tid + u * 1024;
    if (i < NN * 16)
      hreg[u] = *reinterpret_cast<const float4*>(&h1[hbase + (size_t)i * 4]);
  }
#pragma unroll
  for (int u = 0; u < 7; ++u)
    if (ed[u] >= 0) atomicAdd(&cur[ed[u]], 1);
  __syncthreads();

  // ---- scan of padded degrees (x8); dinv ----
  int vincl = 0, myp = 0;
  if (tid < NN) {
    int d = cur[tid];
    dinv[tid] = 1.0f / sqrtf((float)d + 1.0f);
    myp = (d + 7) & ~7;
    vincl = myp;
#pragma unroll
    for (int o = 1; o < 64; o <<= 1) {
      int t = __shfl_up(vincl, o);
      if ((tid & 63) >= o) vincl += t;
    }
    if ((tid & 63) == 63 || tid == NN - 1) wpart[tid >> 6] = vincl;
  }
  __syncthreads();
  if (tid < NN) {
    int base = 0, w = tid >> 6;
    for (int j = 0; j < w; ++j) base += wpart[j];
    int incl = base + vincl;
    off[tid + 1] = incl;
    cur[tid] = incl - myp;
    if (tid == 0) off[0] = 0;
  }
  __syncthreads();

  // ---- stage hl (dinv-scaled) + csr fill ----
#pragma unroll
  for (int u = 0; u < 7; ++u) {
    int i = tid + u * 1024;
    if (i < NN * 16) {
      int n = i >> 4;
      float dn = dinv[n];
      float4 vv = hreg[u];
      vv.x *= dn; vv.y *= dn; vv.z *= dn; vv.w *= dn;
      *reinterpret_cast<float4*>(&hl[i * 4]) = vv;
    }
  }
#pragma unroll
  for (int u = 0; u < 7; ++u)
    if (ed[u] >= 0) {
      int p = atomicAdd(&cur[ed[u]], 1);
      csr[p] = (unsigned short)(es[u] << 6);
    }
  __syncthreads();
  if (tid < NN) {
    int pend = off[tid + 1];
    for (int p = cur[tid]; p < pend; ++p) csr[p] = (unsigned short)(400 * 64);
  }
  __syncthreads();

  // ---- gather1: wave-per-node, b32 rows; score+tanh fused ----
  {
    const float bc1 = b1[lane], pwc1 = pw1[lane];
    float outv[25];
#pragma unroll
    for (int it = 0; it < 25; ++it) {
      int n = it * 16 + wave;
      int e = off[n], end = off[n + 1];
      float a0 = hl[(n << 6) + lane], a1 = 0.f, a2 = 0.f, a3 = 0.f;
      for (; e < end; e += 8) {
        uint4 pk = *reinterpret_cast<const uint4*>(&csr[e]);
        a0 += hl[(pk.x & 0xFFFF) + lane];
        a1 += hl[(pk.x >> 16) + lane];
        a2 += hl[(pk.y & 0xFFFF) + lane];
        a3 += hl[(pk.y >> 16) + lane];
        a0 += hl[(pk.z & 0xFFFF) + lane];
        a1 += hl[(pk.z >> 16) + lane];
        a2 += hl[(pk.w & 0xFFFF) + lane];
        a3 += hl[(pk.w >> 16) + lane];
      }
      float o = fmaxf(fmaf((a0 + a1) + (a2 + a3), dinv[n], bc1), 0.f);
      outv[it] = o;
      float sd = o * pwc1;
      sd += __shfl_xor(sd, 1);
      sd += __shfl_xor(sd, 2);
      sd += __shfl_xor(sd, 4);
      sd += __shfl_xor(sd, 8);
      sd += __shfl_xor(sd, 16);
      sd += __shfl_xor(sd, 32);
      if (lane == 0) sc[n] = tanhf(sd / nrm1_s);
    }
    __syncthreads();   // all reads of hl done
#pragma unroll
    for (int it = 0; it < 25; ++it)
      hl[((it * 16 + wave) << 6) + lane] = outv[it];
  }
  __syncthreads();

  // ---- rank1: 800 threads, 2/node, half j-range each, shfl combine ----
  if (tid < 800) {
    int n = tid >> 1, h = tid & 1;
    float s0 = sc[n];
    int rk = 0;
    int j4b = h * 50;
    for (int j4 = j4b; j4 < j4b + 50; ++j4) {
      float4 sv = *reinterpret_cast<const float4*>(&sc[j4 * 4]);
      int jb = j4 * 4;
      rk += (sv.x > s0) || (sv.x == s0 && jb     < n);
      rk += (sv.y > s0) || (sv.y == s0 && jb + 1 < n);
      rk += (sv.z > s0) || (sv.z == s0 && jb + 2 < n);
      rk += (sv.w > s0) || (sv.w == s0 && jb + 3 < n);
    }
    rk += __shfl_xor(rk, 1);
    if (h == 0) {
      lmap[n] = (rk < 100) ? rk : -1;
      if (rk < 100) sel[rk] = n;
    }
  }
  __syncthreads();

  // ---- hp extract (scaled) + edge remap + zero deg2 ----
  {
    int r = tid >> 4, c4 = (tid & 15) * 4;
    int n = sel[r];
    float s = sc[n];
    float4 vv = *reinterpret_cast<const float4*>(&hl[(n << 6) + c4]);
    vv.x *= s; vv.y *= s; vv.z *= s; vv.w *= s;
    *reinterpret_cast<float4*>(&hp[r * 64 + c4]) = vv;
    if (tid < 576) {
      int r2 = r + 64;
      int n2 = sel[r2];
      float s2 = sc[n2];
      float4 v2 = *reinterpret_cast<const float4*>(&hl[(n2 << 6) + c4]);
      v2.x *= s2; v2.y *= s2; v2.z *= s2; v2.w *= s2;
      *reinterpret_cast<float4*>(&hp[r2 * 64 + c4]) = v2;
    }
  }
#pragma unroll
  for (int u = 0; u < 7; ++u)
    if (ed[u] >= 0) {
      int a = lmap[es[u]], b = lmap[ed[u]];
      if ((a | b) >= 0) { es[u] = a; ed[u] = b; } else ed[u] = -1;
    }
  if (tid >= 512 && tid < 612) cur[tid - 512] = 0;
  __syncthreads();

  // ---- r1 partials (16-wave) + deg2 ----
  {
    float s = 0.f;
    for (int r = wave; r < 100; r += 16) s += hp[r * 64 + lane];
    float* red1 = hl + 8192;                 // hl dead here
    red1[wave * 64 + lane] = s;
  }
#pragma unroll
  for (int u = 0; u < 7; ++u)
    if (ed[u] >= 0) atomicAdd(&cur[ed[u]], 1);
  __syncthreads();

  // ---- scan2 (shfl, pad x4) + r1 combine (spare wave) ----
  {
    int d2 = 0, p2 = 0, v2s = 0;
    if (tid < 100) {
      d2 = cur[tid];
      p2 = (d2 + 3) & ~3;
      v2s = p2;
    }
#pragma unroll
    for (int o = 1; o < 64; o <<= 1) {
      int t = __shfl_up(v2s, o);
      if ((tid & 63) >= o) v2s += t;
    }
    if (tid < 100 && ((tid & 63) == 63 || tid == 99)) wpart[tid >> 6] = v2s;
    if (tid >= 512 && tid < 576) {
      int t = tid - 512;
      const float* red1 = hl + 8192;
      float s = 0.f;
#pragma unroll
      for (int w = 0; w < 16; ++w) s += red1[w * 64 + t];
      r1s[t] = s;
    }
    __syncthreads();
    if (tid < 100) {
      int base = (tid >= 64) ? wpart[0] : 0;
      int incl = base + v2s;
      dinv[tid] = 1.0f / sqrtf((float)d2 + 1.0f);
      off[tid + 1] = incl;
      cur[tid] = incl - p2;
      if (tid == 0) off[0] = 0;
    }
  }
  __syncthreads();
#pragma unroll
  for (int u = 0; u < 7; ++u)
    if (ed[u] >= 0) {
      int p = atomicAdd(&cur[ed[u]], 1);
      csr[p] = (unsigned short)(es[u] << 6);
    }
  __syncthreads();
  float* hl2 = hl + 4096;                   // 101 rows (row 100 = 0)
  float* hpost2 = hl + 4096 + 101 * 64;     // 100 rows
  if (tid < 100) {
    int pend = off[tid + 1];
    for (int p = cur[tid]; p < pend; ++p) csr[p] = (unsigned short)(100 * 64);
  }
  if (tid < 64) hl2[100 * 64 + tid] = 0.f;
  __syncthreads();

  // ---- gemm2: hl2 = dinv2 * (hp @ W2); W2 from global (L1) ----
  {
    float acc[7];
#pragma unroll
    for (int p = 0; p < 7; ++p) acc[p] = 0.f;
    for (int kb = 0; kb < 64; kb += 4) {
      float w0  = W2[(kb + 0) * 64 + lane];
      float w1  = W2[(kb + 1) * 64 + lane];
      float w2v = W2[(kb + 2) * 64 + lane];
      float w3v = W2[(kb + 3) * 64 + lane];
#pragma unroll
      for (int p = 0; p < 7; ++p) {
        int n = wave + p * 16;
        if (n < 100) {
          float4 hv = *reinterpret_cast<const float4*>(&hp[n * 64 + kb]);
          acc[p] = fmaf(hv.x, w0, acc[p]);
          acc[p] = fmaf(hv.y, w1, acc[p]);
          acc[p] = fmaf(hv.z, w2v, acc[p]);
          acc[p] = fmaf(hv.w, w3v, acc[p]);
        }
      }
    }
#pragma unroll
    for (int p = 0; p < 7; ++p) {
      int n = wave + p * 16;
      if (n < 100) hl2[n * 64 + lane] = dinv[n] * acc[p];
    }
  }
  __syncthreads();

  // ---- gather2 + post + score ----
  {
    const float bc2 = b2[lane], pwc2 = pw2[lane];
#pragma unroll
    for (int it = 0; it < 7; ++it) {
      int n = wave + it * 16;
      if (n < 100) {
        float a0 = hl2[n * 64 + lane], a1 = 0.f;
        int e = off[n], end = off[n + 1];
        for (; e < end; e += 4) {
          uint2 pk = *reinterpret_cast<const uint2*>(&csr[e]);
          a0 += hl2[(pk.x & 0xFFFF) + lane];
          a1 += hl2[(pk.x >> 16) + lane];
          a0 += hl2[(pk.y & 0xFFFF) + lane];
          a1 += hl2[(pk.y >> 16) + lane];
        }
        float o = fmaxf(fmaf(a0 + a1, dinv[n], bc2), 0.f);
        hpost2[n * 64 + lane] = o;
        float sd = o * pwc2;
        sd += __shfl_xor(sd, 1);  sd += __shfl_xor(sd, 2);
        sd += __shfl_xor(sd, 4);  sd += __shfl_xor(sd, 8);
        sd += __shfl_xor(sd, 16); sd += __shfl_xor(sd, 32);
        if (lane == 0) sc[n] = tanhf(sd / nrm2_s);
      }
    }
  }
  __syncthreads();

  // ---- rank2: 400 threads, 4/node, quarter j-range, shfl combine ----
  if (tid < 400) {
    int n = tid >> 2, q = tid & 3;
    float s0 = sc[n];
    int rk = 0;
    int j4b = q * 7;
    int j4e = j4b + 7; if (j4e > 25) j4e = 25;
    for (int j4 = j4b; j4 < j4e; ++j4) {
      float4 sv = *reinterpret_cast<const float4*>(&sc[j4 * 4]);
      int jb = j4 * 4;
      rk += (sv.x > s0) || (sv.x == s0 && jb     < n);
      rk += (sv.y > s0) || (sv.y == s0 && jb + 1 < n);
      rk += (sv.z > s0) || (sv.z == s0 && jb + 2 < n);
      rk += (sv.w > s0) || (sv.w == s0 && jb + 3 < n);
    }
    rk += __shfl_xor(rk, 1);
    rk += __shfl_xor(rk, 2);
    if (q == 0) {
      lmap[n] = (rk < 25) ? rk : -1;
      if (rk < 25) sel[rk] = n;
    }
  }
  __syncthreads();

  // ---- hp2 extract + remap + zero deg3 ----
  if (tid < 400) {
    int r = tid >> 4, c4 = (tid & 15) * 4;
    int n = sel[r];
    float s = sc[n];
    float4 vv = *reinterpret_cast<const float4*>(&hpost2[n * 64 + c4]);
    vv.x *= s; vv.y *= s; vv.z *= s; vv.w *= s;
    *reinterpret_cast<float4*>(&hp[r * 64 + c4]) = vv;
  }
#pragma unroll
  for (int u = 0; u < 7; ++u)
    if (ed[u] >= 0) {
      int a = lmap[es[u]], b = lmap[ed[u]];
      if ((a | b) >= 0) { es[u] = a; ed[u] = b; } else ed[u] = -1;
    }
  if (tid >= 512 && tid < 537) cur[tid - 512] = 0;
  __syncthreads();

  // ---- r2 partials (16-wave) + deg3 ----
  {
    float s = 0.f;
    for (int r = wave; r < 25; r += 16) s += hp[r * 64 + lane];
    float* red2 = hl + 8192;                 // hl2/hpost2 dead here
    red2[wave * 64 + lane] = s;
  }
#pragma unroll
  for (int u = 0; u < 7; ++u)
    if (ed[u] >= 0) atomicAdd(&cur[ed[u]], 1);
  __syncthreads();

  // ---- scan3 (single-wave shfl, pad x4) + r2 combine (spare wave) ----
  {
    int d3 = 0, p3 = 0, v3s = 0;
    if (tid < 25) {
      d3 = cur[tid];
      p3 = (d3 + 3) & ~3;
      v3s = p3;
    }
    if (tid < 64) {
#pragma unroll
      for (int o = 1; o < 32; o <<= 1) {
        int t = __shfl_up(v3s, o);
        if (lane >= o) v3s += t;
      }
    }
    if (tid >= 512 && tid < 576) {
      int t = tid - 512;
      const float* red2 = hl + 8192;
      float s = 0.f;
#pragma unroll
      for (int w = 0; w < 16; ++w) s += red2[w * 64 + t];
      r2s[t] = s;
    }
    __syncthreads();
    if (tid < 25) {
      dinv[tid] = 1.0f / sqrtf((float)d3 + 1.0f);
      off[tid + 1] = v3s;
      cur[tid] = v3s - p3;
      if (tid == 0) off[0] = 0;
    }
  }
  __syncthreads();
#pragma unroll
  for (int u = 0; u < 7; ++u)
    if (ed[u] >= 0) {
      int p = atomicAdd(&cur[ed[u]], 1);
      csr[p] = (unsigned short)(es[u] << 6);
    }
  __syncthreads();
  float* hl3 = hl + 4096;                   // 26 rows (row 25 = 0)
  if (tid < 25) {
    int pend = off[tid + 1];
    for (int p = cur[tid]; p < pend; ++p) csr[p] = (unsigned short)(25 * 64);
  }
  if (tid < 64) hl3[25 * 64 + tid] = 0.f;
  __syncthreads();

  // ---- gemm3 (P=2); W3 from global ----
  {
    float a0c = 0.f, a1c = 0.f;
    const int n1 = wave + 16;
    for (int kb = 0; kb < 64; kb += 4) {
      float w0  = W3[(kb + 0) * 64 + lane];
      float w1  = W3[(kb + 1) * 64 + lane];
      float w2v = W3[(kb + 2) * 64 + lane];
      float w3v = W3[(kb + 3) * 64 + lane];
      {
        float4 hv = *reinterpret_cast<const float4*>(&hp[wave * 64 + kb]);
        a0c = fmaf(hv.x, w0, a0c);
        a0c = fmaf(hv.y, w1, a0c);
        a0c = fmaf(hv.z, w2v, a0c);
        a0c = fmaf(hv.w, w3v, a0c);
      }
      if (n1 < 25) {
        float4 hv = *reinterpret_cast<const float4*>(&hp[n1 * 64 + kb]);
        a1c = fmaf(hv.x, w0, a1c);
        a1c = fmaf(hv.y, w1, a1c);
        a1c = fmaf(hv.z, w2v, a1c);
        a1c = fmaf(hv.w, w3v, a1c);
      }
    }
    hl3[wave * 64 + lane] = dinv[wave] * a0c;
    if (n1 < 25) hl3[n1 * 64 + lane] = dinv[n1] * a1c;
  }
  __syncthreads();

  // ---- gather3 + r3 partials ----
  {
    const float bc3 = b3[lane];
    float part = 0.f;
#pragma unroll
    for (int it = 0; it < 2; ++it) {
      int n = wave + it * 16;
      if (n < 25) {
        float a0 = hl3[n * 64 + lane], a1 = 0.f;
        int e = off[n], end = off[n + 1];
        for (; e < end; e += 4) {
          uint2 pk = *reinterpret_cast<const uint2*>(&csr[e]);
          a0 += hl3[(pk.x & 0xFFFF) + lane];
          a1 += hl3[(pk.x >> 16) + lane];
          a0 += hl3[(pk.y & 0xFFFF) + lane];
          a1 += hl3[(pk.y >> 16) + lane];
        }
        part += fmaxf(fmaf(a0 + a1, dinv[n], bc3), 0.f);
      }
    }
    float* red = hl + 8192;
    red[wave * 64 + lane] = part;
  }
  __syncthreads();

  // ---- final linear ----
  if (tid < 64) {
    float* red = hl + 8192;
    float r3c = 0.f;
#pragma unroll
    for (int w = 0; w < 16; ++w) r3c += red[w * 64 + tid];
    float f1 = r2s[tid], f2 = r1s[tid];
    float p0 = r3c * Wl[tid * 2 + 0] + f1 * Wl[(64 + tid) * 2 + 0] + f2 * Wl[(128 + tid) * 2 + 0];
    float p1 = r3c * Wl[tid * 2 + 1] + f1 * Wl[(64 + tid) * 2 + 1] + f2 * Wl[(128 + tid) * 2 + 1];
#pragma unroll
    for (int o = 32; o; o >>= 1) {
      p0 += __shfl_xor(p0, o);
      p1 += __shfl_xor(p1, o);
    }
    if (tid == 0) {
      out[g * 2 + 0] = p0 + bl[0];
      out[g * 2 + 1] = p1 + bl[1];
    }
  }
}

// ---------------------------------------------------------------------------
extern "C" void kernel_launch(void* const* d_in, const int* in_sizes, int n_in,
                              void* d_out, int out_size, void* d_ws, size_t ws_size,
                              hipStream_t stream) {
  const float* x   = (const float*)d_in[0];
  const int*   src = (const int*)d_in[1];
  const int*   dst = (const int*)d_in[2];
  const float* W1  = (const float*)d_in[4];
  const float* b1  = (const float*)d_in[5];
  const float* W2  = (const float*)d_in[6];
  const float* b2  = (const float*)d_in[7];
  const float* W3  = (const float*)d_in[8];
  const float* b3  = (const float*)d_in[9];
  const float* pw1 = (const float*)d_in[10];
  const float* pw2 = (const float*)d_in[11];
  const float* Wl  = (const float*)d_in[12];
  const float* bl  = (const float*)d_in[13];
  float* out = (float*)d_out;

  float* h1 = (float*)d_ws;   // 102400 x 64 floats

  gemm64x<128><<<dim3(BGR, 7), 256, 0, stream>>>(x, W1, h1);
  mega<<<BGR, 1024, 0, stream>>>(h1, src, dst, b1, pw1, W2, b2, pw2,
                                 W3, b3, Wl, bl, out);
}